// Round 5
// baseline (1291.599 us; speedup 1.0000x reference)
//
#include <hip/hip_runtime.h>

#define F_IN  128
#define F_HID 8
#define F_OUT 16
#define BSH   6              // bucket = 64 consecutive dst nodes
#define BW    (1 << BSH)

// edge_index arrives as int32 [2][E] (harness downcasts int64 inputs).
// agg[i] = dis[i] * ( sum_{s in N(i)} g[s] + g[i] ),  g = h * dis.
// CSR build is bucketed: scatter into per-bucket regions whose cursors are hot,
// so 64B lines fill while resident (fixes the 392MB write amplification of R3/R4).

__global__ void init_cnt(int* __restrict__ cnt, int* __restrict__ cursor, int n) {
    int i = blockIdx.x * blockDim.x + threadIdx.x;
    if (i < n) cnt[i] = 0;
    if (i == 0) *cursor = 0;
}

__global__ void count_dst(const int* __restrict__ ei, int* __restrict__ cnt, int E) {
    int t = blockIdx.x * blockDim.x + threadIdx.x;
    int base = t * 4;
    if (base + 3 < E) {
        int4 v = *(const int4*)(ei + E + base);
        atomicAdd(&cnt[v.x], 1);
        atomicAdd(&cnt[v.y], 1);
        atomicAdd(&cnt[v.z], 1);
        atomicAdd(&cnt[v.w], 1);
    } else if (base < E) {
        for (int k = base; k < E; k++) atomicAdd(&cnt[ei[E + k]], 1);
    }
}

// per-bucket edge count + contiguous region allocation (unordered is fine)
__global__ void bucket_alloc(const int* __restrict__ cnt,
                             int* __restrict__ bucket_start, int* __restrict__ bucket_cnt,
                             int* __restrict__ bucket_cur, int* __restrict__ stage_cur,
                             int* __restrict__ cursor, int n, int B) {
    int b = blockIdx.x * blockDim.x + threadIdx.x;
    if (b >= B) return;
    int lo = b << BSH, hi = min(n, lo + BW);
    int bs = 0;
    for (int i = lo; i < hi; i++) bs += cnt[i];
    int r = atomicAdd(cursor, bs);
    bucket_cnt[b]   = bs;
    bucket_start[b] = r;
    bucket_cur[b]   = r;
    stage_cur[b]    = r;
}

// rows allocated within their bucket's region; dis = rsqrt(deg)
__global__ void calc_offsets(const int* __restrict__ cnt, float* __restrict__ dis,
                             int* __restrict__ row_start, int* __restrict__ bucket_cur, int n) {
    int i = blockIdx.x * blockDim.x + threadIdx.x;
    if (i >= n) return;
    int c = cnt[i];
    dis[i] = rsqrtf((float)(c + 1));
    row_start[i] = atomicAdd(&bucket_cur[i >> BSH], c);
}

// stage[pos] = (src<<6) | (dst&63), grouped by dst-bucket; cursor claims cluster in time
__global__ __launch_bounds__(256) void stage_bin(const int* __restrict__ ei,
                                                 int* __restrict__ stage_cur,
                                                 int* __restrict__ stage, int E) {
    int e = blockIdx.x * blockDim.x + threadIdx.x;
    if (e >= E) return;
    int s = ei[e];
    int d = ei[E + e];
    int pos = atomicAdd(&stage_cur[d >> BSH], 1);
    stage[pos] = (s << BSH) | (d & (BW - 1));
}

// one block per bucket: LDS row cursors, scatter src into the bucket's warm CSR segment
__global__ __launch_bounds__(256) void scatter_csr(const int* __restrict__ stage,
                                                   const int* __restrict__ bucket_start,
                                                   const int* __restrict__ bucket_cnt,
                                                   const int* __restrict__ row_start,
                                                   int* __restrict__ csr, int n) {
    __shared__ int cur[BW];
    int b = blockIdx.x;
    int node_base = b << BSH;
    if (threadIdx.x < BW && node_base + threadIdx.x < n)
        cur[threadIdx.x] = row_start[node_base + threadIdx.x];
    __syncthreads();
    int beg = bucket_start[b];
    int num = bucket_cnt[b];
    for (int k = threadIdx.x; k < num; k += blockDim.x) {
        int v = stage[beg + k];
        int pos = atomicAdd(&cur[v & (BW - 1)], 1);
        csr[pos] = v >> BSH;
    }
}

// ---------------- layer-1 GEMM: g1 = (x @ W1) * dis ----------------
__global__ __launch_bounds__(256) void gemm1(const float* __restrict__ x,
                                             const float* __restrict__ W1,
                                             const float* __restrict__ dis,
                                             float* __restrict__ g1, int n) {
    __shared__ float w[F_IN * F_HID];  // 4 KB
    for (int i = threadIdx.x; i < F_IN * F_HID; i += blockDim.x) w[i] = W1[i];
    __syncthreads();
    int node = blockIdx.x * blockDim.x + threadIdx.x;
    if (node >= n) return;
    const float4* xr = (const float4*)(x + (size_t)node * F_IN);
    float acc[F_HID];
#pragma unroll
    for (int f = 0; f < F_HID; f++) acc[f] = 0.0f;
#pragma unroll
    for (int j = 0; j < F_IN / 4; j++) {
        float4 v = xr[j];
        const float* wr = &w[j * 4 * F_HID];
#pragma unroll
        for (int f = 0; f < F_HID; f++)
            acc[f] += v.x * wr[f] + v.y * wr[F_HID + f] + v.z * wr[2 * F_HID + f] + v.w * wr[3 * F_HID + f];
    }
    float d = dis[node];
    float4* gp = (float4*)(g1 + (size_t)node * F_HID);
    gp[0] = make_float4(acc[0] * d, acc[1] * d, acc[2] * d, acc[3] * d);
    gp[1] = make_float4(acc[4] * d, acc[5] * d, acc[6] * d, acc[7] * d);
}

// ---------------- aggregation: agg[i] = dis[i] * (sum g[src] + g[i]); 8 lanes/node ----------------
__global__ __launch_bounds__(256) void aggregate(const int* __restrict__ csr,
                                                 const int* __restrict__ row_start,
                                                 const int* __restrict__ cnt,
                                                 const float* __restrict__ dis,
                                                 const float* __restrict__ g,
                                                 float* __restrict__ agg, int n) {
    int t = blockIdx.x * blockDim.x + threadIdx.x;
    int node = t >> 3;
    int f = t & 7;
    if (node >= n) return;
    int beg = row_start[node];
    int c   = cnt[node];
    float acc = g[(size_t)node * F_HID + f];        // self-loop
    for (int j = 0; j < c; j++) {
        int s = csr[beg + j];                       // uniform across the 8-lane group
        acc += g[(size_t)s * F_HID + f];
    }
    agg[(size_t)node * F_HID + f] = acc * dis[node];
}

// ---------------- g2 = relu(agg1 + b1) * dis ----------------
__global__ __launch_bounds__(256) void relu_init(const float* __restrict__ b1,
                                                 const float* __restrict__ dis,
                                                 const float* __restrict__ agg1,
                                                 float* __restrict__ g2, int n) {
    int i = blockIdx.x * blockDim.x + threadIdx.x;
    if (i >= n) return;
    float d = dis[i];
    const float4* a = (const float4*)(agg1 + (size_t)i * F_HID);
    float4 lo = a[0], hi = a[1];
    lo.x = fmaxf(lo.x + b1[0], 0.0f) * d;
    lo.y = fmaxf(lo.y + b1[1], 0.0f) * d;
    lo.z = fmaxf(lo.z + b1[2], 0.0f) * d;
    lo.w = fmaxf(lo.w + b1[3], 0.0f) * d;
    hi.x = fmaxf(hi.x + b1[4], 0.0f) * d;
    hi.y = fmaxf(hi.y + b1[5], 0.0f) * d;
    hi.z = fmaxf(hi.z + b1[6], 0.0f) * d;
    hi.w = fmaxf(hi.w + b1[7], 0.0f) * d;
    float4* o = (float4*)(g2 + (size_t)i * F_HID);
    o[0] = lo; o[1] = hi;
}

// ---------------- out = agg2 @ W2 + b2 ----------------
__global__ __launch_bounds__(256) void gemm2(const float* __restrict__ agg2,
                                             const float* __restrict__ W2,
                                             const float* __restrict__ b2,
                                             float* __restrict__ out, int n) {
    __shared__ float w[F_HID * F_OUT];
    __shared__ float bb[F_OUT];
    if (threadIdx.x < F_HID * F_OUT) w[threadIdx.x] = W2[threadIdx.x];
    if (threadIdx.x < F_OUT) bb[threadIdx.x] = b2[threadIdx.x];
    __syncthreads();
    int node = blockIdx.x * blockDim.x + threadIdx.x;
    if (node >= n) return;
    const float4* ap = (const float4*)(agg2 + (size_t)node * F_HID);
    float4 lo = ap[0], hi = ap[1];
    float a[F_HID] = {lo.x, lo.y, lo.z, lo.w, hi.x, hi.y, hi.z, hi.w};
    float o[F_OUT];
#pragma unroll
    for (int f = 0; f < F_OUT; f++) o[f] = bb[f];
#pragma unroll
    for (int k = 0; k < F_HID; k++) {
#pragma unroll
        for (int f = 0; f < F_OUT; f++) o[f] += a[k] * w[k * F_OUT + f];
    }
    float4* op = (float4*)(out + (size_t)node * F_OUT);
    op[0] = make_float4(o[0], o[1], o[2], o[3]);
    op[1] = make_float4(o[4], o[5], o[6], o[7]);
    op[2] = make_float4(o[8], o[9], o[10], o[11]);
    op[3] = make_float4(o[12], o[13], o[14], o[15]);
}

extern "C" void kernel_launch(void* const* d_in, const int* in_sizes, int n_in,
                              void* d_out, int out_size, void* d_ws, size_t ws_size,
                              hipStream_t stream) {
    const float* x  = (const float*)d_in[0];
    const int*   ei = (const int*)d_in[1];
    const float* W1 = (const float*)d_in[2];
    const float* b1 = (const float*)d_in[3];
    const float* W2 = (const float*)d_in[4];
    const float* b2 = (const float*)d_in[5];
    float* out = (float*)d_out;

    const int N = in_sizes[0] / F_IN;
    const int E = in_sizes[1] / 2;
    const int B = (N + BW - 1) >> BSH;

    // ws (4B units): stage[E] | csr[E] | dis[N] | bufA[8N] | bufB[8N] | cnt[N] | row_start[N]
    //                | bucket_start[B] | bucket_cnt[B] | bucket_cur[B] | stage_cur[B] | cursor[1]
    int*   stage        = (int*)d_ws;
    int*   csr          = stage + E;
    float* dis          = (float*)(csr + E);
    float* bufA         = dis + N;
    float* bufB         = bufA + (size_t)N * F_HID;
    int*   cnt          = (int*)(bufB + (size_t)N * F_HID);
    int*   row_start    = cnt + N;
    int*   bucket_start = row_start + N;
    int*   bucket_cnt   = bucket_start + B;
    int*   bucket_cur   = bucket_cnt + B;
    int*   stage_cur    = bucket_cur + B;
    int*   cursor       = stage_cur + B;

    const int BT = 256;
    dim3 blkN((N + BT - 1) / BT), blkE((E + BT - 1) / BT), thr(BT);
    dim3 blkE4((E / 4 + BT) / BT);
    dim3 blkB((B + BT - 1) / BT);
    dim3 blkA(((size_t)N * F_HID + BT - 1) / BT);

    init_cnt    <<<blkN,  thr, 0, stream>>>(cnt, cursor, N);
    count_dst   <<<blkE4, thr, 0, stream>>>(ei, cnt, E);
    bucket_alloc<<<blkB,  thr, 0, stream>>>(cnt, bucket_start, bucket_cnt, bucket_cur, stage_cur, cursor, N, B);
    calc_offsets<<<blkN,  thr, 0, stream>>>(cnt, dis, row_start, bucket_cur, N);
    stage_bin   <<<blkE,  thr, 0, stream>>>(ei, stage_cur, stage, E);
    scatter_csr <<<dim3(B), thr, 0, stream>>>(stage, bucket_start, bucket_cnt, row_start, csr, N);
    gemm1       <<<blkN,  thr, 0, stream>>>(x, W1, dis, bufA, N);
    aggregate   <<<blkA,  thr, 0, stream>>>(csr, row_start, cnt, dis, bufA, bufB, N);
    relu_init   <<<blkN,  thr, 0, stream>>>(b1, dis, bufB, bufA, N);
    aggregate   <<<blkA,  thr, 0, stream>>>(csr, row_start, cnt, dis, bufA, bufB, N);
    gemm2       <<<blkN,  thr, 0, stream>>>(bufB, W2, b2, out, N);
}

// Round 6
// 1249.217 us; speedup vs baseline: 1.0339x; 1.0339x over previous
//
#include <hip/hip_runtime.h>

#define F_IN  128
#define F_HID 8
#define F_OUT 16

#define SBSH  9                 // coarse bucket = 512 consecutive dst nodes
#define SBW   (1 << SBSH)
#define MAXB  400               // supports N <= 204800
#define BIN_CAP  32             // LDS entries per bucket
#define FLUSH_G  16             // flush granularity (16 ints = 64B line)

// edge_index arrives as int32 [2][E].
// agg[i] = dis[i] * ( sum_{s in N(i)} g[s] + g[i] ),  g = h * dis.
// Scattered 4B stores cost ~64B writeback each (cross-XCD partial-line thrash,
// R3-R5 evidence). Fix: LDS write-combining — every global store in the CSR
// build is a contiguous >=64B run written by one thread into a region whose
// lines are completed quickly.

__global__ void init_cnt(int* __restrict__ cnt, int* __restrict__ cursor, int n) {
    int i = blockIdx.x * blockDim.x + threadIdx.x;
    if (i < n) cnt[i] = 0;
    if (i == 0) *cursor = 0;
}

__global__ void count_dst(const int* __restrict__ ei, int* __restrict__ cnt, int E) {
    int t = blockIdx.x * blockDim.x + threadIdx.x;
    int base = t * 4;
    if (base + 3 < E) {
        int4 v = *(const int4*)(ei + E + base);
        atomicAdd(&cnt[v.x], 1);
        atomicAdd(&cnt[v.y], 1);
        atomicAdd(&cnt[v.z], 1);
        atomicAdd(&cnt[v.w], 1);
    } else if (base < E) {
        for (int k = base; k < E; k++) atomicAdd(&cnt[ei[E + k]], 1);
    }
}

// per-coarse-bucket edge count + contiguous region alloc; two cursor copies:
// gcur (stage fill) and bucket_cur (row allocation within region)
__global__ void bucket_alloc(const int* __restrict__ cnt,
                             int* __restrict__ coarse_start, int* __restrict__ coarse_cnt,
                             int* __restrict__ bucket_cur, int* __restrict__ gcur,
                             int* __restrict__ cursor, int n, int B) {
    int b = blockIdx.x * blockDim.x + threadIdx.x;
    if (b >= B) return;
    int lo = b << SBSH, hi = min(n, lo + SBW);
    int bs = 0;
    for (int i = lo; i < hi; i++) bs += cnt[i];
    int r = atomicAdd(cursor, bs);
    coarse_cnt[b]   = bs;
    coarse_start[b] = r;
    bucket_cur[b]   = r;
    gcur[b]         = r;
}

__global__ void calc_offsets(const int* __restrict__ cnt, float* __restrict__ dis,
                             int* __restrict__ row_start, int* __restrict__ bucket_cur, int n) {
    int i = blockIdx.x * blockDim.x + threadIdx.x;
    if (i >= n) return;
    int c = cnt[i];
    dis[i] = rsqrtf((float)(c + 1));
    row_start[i] = atomicAdd(&bucket_cur[i >> SBSH], c);
}

// LDS write-combined binning: stage[...] = (src<<9)|(dst&511), grouped by coarse bucket.
// All global stores are contiguous runs of FLUSH_G..BIN_CAP ints by one thread.
__global__ __launch_bounds__(256) void stage_bin(const int* __restrict__ ei,
                                                 int* __restrict__ gcur,
                                                 int* __restrict__ stage,
                                                 int E, int B, int per_block) {
    __shared__ int bin_cnt[MAXB];
    __shared__ int bin_buf[MAXB * BIN_CAP];   // ~50KB
    for (int i = threadIdx.x; i < B; i += blockDim.x) bin_cnt[i] = 0;
    __syncthreads();
    int base = blockIdx.x * per_block;
    int end  = min(E, base + per_block);
    for (int it = base; it < end; it += blockDim.x) {
        int e = it + (int)threadIdx.x;
        if (e < end) {
            int s = ei[e];
            int d = ei[E + e];
            int b = d >> SBSH;
            int val = (s << SBSH) | (d & (SBW - 1));
            int pos = atomicAdd(&bin_cnt[b], 1);
            if (pos < BIN_CAP) {
                bin_buf[b * BIN_CAP + pos] = val;
            } else {                                  // overflow (P ~ 1e-15): direct store
                int gp = atomicAdd(&gcur[b], 1);
                stage[gp] = val;
            }
        }
        __syncthreads();
        for (int b2 = threadIdx.x; b2 < B; b2 += blockDim.x) {
            int c = min(bin_cnt[b2], BIN_CAP);
            if (c >= FLUSH_G) {
                int m = c & ~(FLUSH_G - 1);
                int r = atomicAdd(&gcur[b2], m);
                const int* src = &bin_buf[b2 * BIN_CAP];
                for (int k = 0; k < m; k++) stage[r + k] = src[k];       // contiguous run
                for (int k = m; k < c; k++) bin_buf[b2 * BIN_CAP + (k - m)] = src[k];
                bin_cnt[b2] = c - m;
            } else {
                bin_cnt[b2] = c;
            }
        }
        __syncthreads();
    }
    for (int b2 = threadIdx.x; b2 < B; b2 += blockDim.x) {   // final flush
        int c = min(bin_cnt[b2], BIN_CAP);
        if (c > 0) {
            int r = atomicAdd(&gcur[b2], c);
            for (int k = 0; k < c; k++) stage[r + k] = bin_buf[b2 * BIN_CAP + k];
        }
    }
}

// one block per coarse bucket: 512 LDS row cursors; scatter into the bucket's
// ~64KB CSR segment (single-CU-owned -> writes merge in its XCD L2)
__global__ __launch_bounds__(256) void scatter_csr(const int* __restrict__ stage,
                                                   const int* __restrict__ coarse_start,
                                                   const int* __restrict__ coarse_cnt,
                                                   const int* __restrict__ row_start,
                                                   int* __restrict__ csr, int n) {
    __shared__ int cur[SBW];
    int b = blockIdx.x;
    int nb = b << SBSH;
    for (int i = threadIdx.x; i < SBW; i += blockDim.x)
        if (nb + i < n) cur[i] = row_start[nb + i];
    __syncthreads();
    int beg = coarse_start[b];
    int num = coarse_cnt[b];
    for (int k = threadIdx.x; k < num; k += blockDim.x) {
        int v = stage[beg + k];
        int pos = atomicAdd(&cur[v & (SBW - 1)], 1);
        csr[pos] = v >> SBSH;
    }
}

// ---------------- layer-1 GEMM: g1 = (x @ W1) * dis ----------------
__global__ __launch_bounds__(256) void gemm1(const float* __restrict__ x,
                                             const float* __restrict__ W1,
                                             const float* __restrict__ dis,
                                             float* __restrict__ g1, int n) {
    __shared__ float w[F_IN * F_HID];  // 4 KB
    for (int i = threadIdx.x; i < F_IN * F_HID; i += blockDim.x) w[i] = W1[i];
    __syncthreads();
    int node = blockIdx.x * blockDim.x + threadIdx.x;
    if (node >= n) return;
    const float4* xr = (const float4*)(x + (size_t)node * F_IN);
    float acc[F_HID];
#pragma unroll
    for (int f = 0; f < F_HID; f++) acc[f] = 0.0f;
#pragma unroll
    for (int j = 0; j < F_IN / 4; j++) {
        float4 v = xr[j];
        const float* wr = &w[j * 4 * F_HID];
#pragma unroll
        for (int f = 0; f < F_HID; f++)
            acc[f] += v.x * wr[f] + v.y * wr[F_HID + f] + v.z * wr[2 * F_HID + f] + v.w * wr[3 * F_HID + f];
    }
    float d = dis[node];
    float4* gp = (float4*)(g1 + (size_t)node * F_HID);
    gp[0] = make_float4(acc[0] * d, acc[1] * d, acc[2] * d, acc[3] * d);
    gp[1] = make_float4(acc[4] * d, acc[5] * d, acc[6] * d, acc[7] * d);
}

// ---------------- aggregation: agg[i] = dis[i] * (sum g[src] + g[i]); 8 lanes/node ----------------
__global__ __launch_bounds__(256) void aggregate(const int* __restrict__ csr,
                                                 const int* __restrict__ row_start,
                                                 const int* __restrict__ cnt,
                                                 const float* __restrict__ dis,
                                                 const float* __restrict__ g,
                                                 float* __restrict__ agg, int n) {
    int t = blockIdx.x * blockDim.x + threadIdx.x;
    int node = t >> 3;
    int f = t & 7;
    if (node >= n) return;
    int beg = row_start[node];
    int c   = cnt[node];
    float acc = g[(size_t)node * F_HID + f];        // self-loop
    for (int j = 0; j < c; j++) {
        int s = csr[beg + j];                       // uniform across the 8-lane group
        acc += g[(size_t)s * F_HID + f];
    }
    agg[(size_t)node * F_HID + f] = acc * dis[node];
}

// ---------------- g2 = relu(agg1 + b1) * dis ----------------
__global__ __launch_bounds__(256) void relu_init(const float* __restrict__ b1,
                                                 const float* __restrict__ dis,
                                                 const float* __restrict__ agg1,
                                                 float* __restrict__ g2, int n) {
    int i = blockIdx.x * blockDim.x + threadIdx.x;
    if (i >= n) return;
    float d = dis[i];
    const float4* a = (const float4*)(agg1 + (size_t)i * F_HID);
    float4 lo = a[0], hi = a[1];
    lo.x = fmaxf(lo.x + b1[0], 0.0f) * d;
    lo.y = fmaxf(lo.y + b1[1], 0.0f) * d;
    lo.z = fmaxf(lo.z + b1[2], 0.0f) * d;
    lo.w = fmaxf(lo.w + b1[3], 0.0f) * d;
    hi.x = fmaxf(hi.x + b1[4], 0.0f) * d;
    hi.y = fmaxf(hi.y + b1[5], 0.0f) * d;
    hi.z = fmaxf(hi.z + b1[6], 0.0f) * d;
    hi.w = fmaxf(hi.w + b1[7], 0.0f) * d;
    float4* o = (float4*)(g2 + (size_t)i * F_HID);
    o[0] = lo; o[1] = hi;
}

// ---------------- out = agg2 @ W2 + b2 ----------------
__global__ __launch_bounds__(256) void gemm2(const float* __restrict__ agg2,
                                             const float* __restrict__ W2,
                                             const float* __restrict__ b2,
                                             float* __restrict__ out, int n) {
    __shared__ float w[F_HID * F_OUT];
    __shared__ float bb[F_OUT];
    if (threadIdx.x < F_HID * F_OUT) w[threadIdx.x] = W2[threadIdx.x];
    if (threadIdx.x < F_OUT) bb[threadIdx.x] = b2[threadIdx.x];
    __syncthreads();
    int node = blockIdx.x * blockDim.x + threadIdx.x;
    if (node >= n) return;
    const float4* ap = (const float4*)(agg2 + (size_t)node * F_HID);
    float4 lo = ap[0], hi = ap[1];
    float a[F_HID] = {lo.x, lo.y, lo.z, lo.w, hi.x, hi.y, hi.z, hi.w};
    float o[F_OUT];
#pragma unroll
    for (int f = 0; f < F_OUT; f++) o[f] = bb[f];
#pragma unroll
    for (int k = 0; k < F_HID; k++) {
#pragma unroll
        for (int f = 0; f < F_OUT; f++) o[f] += a[k] * w[k * F_OUT + f];
    }
    float4* op = (float4*)(out + (size_t)node * F_OUT);
    op[0] = make_float4(o[0], o[1], o[2], o[3]);
    op[1] = make_float4(o[4], o[5], o[6], o[7]);
    op[2] = make_float4(o[8], o[9], o[10], o[11]);
    op[3] = make_float4(o[12], o[13], o[14], o[15]);
}

extern "C" void kernel_launch(void* const* d_in, const int* in_sizes, int n_in,
                              void* d_out, int out_size, void* d_ws, size_t ws_size,
                              hipStream_t stream) {
    const float* x  = (const float*)d_in[0];
    const int*   ei = (const int*)d_in[1];
    const float* W1 = (const float*)d_in[2];
    const float* b1 = (const float*)d_in[3];
    const float* W2 = (const float*)d_in[4];
    const float* b2 = (const float*)d_in[5];
    float* out = (float*)d_out;

    const int N = in_sizes[0] / F_IN;
    const int E = in_sizes[1] / 2;
    const int B = (N + SBW - 1) >> SBSH;   // 391 for N=200000 (MAXB=400 supports N<=204800)

    // ws (4B units): stage[E] | csr[E] | dis[N] | bufA[8N] | bufB[8N] | cnt[N] | row_start[N]
    //                | coarse_start[B] | coarse_cnt[B] | bucket_cur[B] | gcur[B] | cursor[1]
    int*   stage        = (int*)d_ws;
    int*   csr          = stage + E;
    float* dis          = (float*)(csr + E);
    float* bufA         = dis + N;
    float* bufB         = bufA + (size_t)N * F_HID;
    int*   cnt          = (int*)(bufB + (size_t)N * F_HID);
    int*   row_start    = cnt + N;
    int*   coarse_start = row_start + N;
    int*   coarse_cnt   = coarse_start + B;
    int*   bucket_cur   = coarse_cnt + B;
    int*   gcur         = bucket_cur + B;
    int*   cursor       = gcur + B;

    const int BT = 256;
    dim3 blkN((N + BT - 1) / BT), thr(BT);
    dim3 blkE4((E / 4 + BT) / BT);
    dim3 blkB((B + BT - 1) / BT);
    dim3 blkA(((size_t)N * F_HID + BT - 1) / BT);

    const int SBLK = 768;                          // ~3 blocks/CU at 51KB LDS
    const int per_block = (E + SBLK - 1) / SBLK;

    init_cnt    <<<blkN,  thr, 0, stream>>>(cnt, cursor, N);
    count_dst   <<<blkE4, thr, 0, stream>>>(ei, cnt, E);
    bucket_alloc<<<blkB,  thr, 0, stream>>>(cnt, coarse_start, coarse_cnt, bucket_cur, gcur, cursor, N, B);
    calc_offsets<<<blkN,  thr, 0, stream>>>(cnt, dis, row_start, bucket_cur, N);
    stage_bin   <<<dim3(SBLK), thr, 0, stream>>>(ei, gcur, stage, E, B, per_block);
    scatter_csr <<<dim3(B), thr, 0, stream>>>(stage, coarse_start, coarse_cnt, row_start, csr, N);
    gemm1       <<<blkN,  thr, 0, stream>>>(x, W1, dis, bufA, N);
    aggregate   <<<blkA,  thr, 0, stream>>>(csr, row_start, cnt, dis, bufA, bufB, N);
    relu_init   <<<blkN,  thr, 0, stream>>>(b1, dis, bufB, bufA, N);
    aggregate   <<<blkA,  thr, 0, stream>>>(csr, row_start, cnt, dis, bufA, bufB, N);
    gemm2       <<<blkN,  thr, 0, stream>>>(bufB, W2, b2, out, N);
}

// Round 7
// 921.849 us; speedup vs baseline: 1.4011x; 1.3551x over previous
//
#include <hip/hip_runtime.h>

#define F_IN  128
#define F_HID 8
#define F_OUT 16

#define SBSH  9                 // coarse bucket = 512 consecutive dst nodes
#define SBW   (1 << SBSH)
#define MAXB  400               // supports N <= 204800
#define BIN_CAP  32             // LDS entries per bucket (stage_bin)
#define FLUSH_G  16             // flush granularity (16 ints = 64B line)

// edge_index arrives as int32 [2][E].
// agg[i] = dis[i] * ( sum_{s in N(i)} g[s] + g[i] ),  g = h * dis.
// Scattered 4B stores cost ~64B writeback each (R3-R5 evidence) -> all CSR-build
// stores are LDS-write-combined contiguous runs. Row offsets via per-bucket LDS
// prefix scan (R6): the R5 calc_offsets atomicAdd had 64 same-address lanes/wave
// (non-uniform addend -> no HW coalescing) = 287us of pure RMW serialization.

__global__ void init_cnt(int* __restrict__ cnt, int* __restrict__ cursor, int n) {
    int i = blockIdx.x * blockDim.x + threadIdx.x;
    if (i < n) cnt[i] = 0;
    if (i == 0) *cursor = 0;
}

__global__ void count_dst(const int* __restrict__ ei, int* __restrict__ cnt, int E) {
    int t = blockIdx.x * blockDim.x + threadIdx.x;
    int base = t * 4;
    if (base + 3 < E) {
        int4 v = *(const int4*)(ei + E + base);
        atomicAdd(&cnt[v.x], 1);
        atomicAdd(&cnt[v.y], 1);
        atomicAdd(&cnt[v.z], 1);
        atomicAdd(&cnt[v.w], 1);
    } else if (base < E) {
        for (int k = base; k < E; k++) atomicAdd(&cnt[ei[E + k]], 1);
    }
}

// one block per coarse bucket: coalesced reduction of cnt -> contiguous region alloc
__global__ __launch_bounds__(256) void bucket_alloc(const int* __restrict__ cnt,
                                                    int* __restrict__ coarse_start,
                                                    int* __restrict__ coarse_cnt,
                                                    int* __restrict__ gcur,
                                                    int* __restrict__ cursor, int n) {
    __shared__ int red[256];
    int b = blockIdx.x;
    int i0 = (b << SBSH) + threadIdx.x;
    int i1 = i0 + 256;
    int s = ((i0 < n) ? cnt[i0] : 0) + ((i1 < n) ? cnt[i1] : 0);
    red[threadIdx.x] = s;
    __syncthreads();
    for (int off = 128; off > 0; off >>= 1) {
        if (threadIdx.x < off) red[threadIdx.x] += red[threadIdx.x + off];
        __syncthreads();
    }
    if (threadIdx.x == 0) {
        int bs = red[0];
        int r = atomicAdd(cursor, bs);   // 391 atomics on one address: negligible
        coarse_cnt[b]   = bs;
        coarse_start[b] = r;
        gcur[b]         = r;
    }
}

// LDS write-combined binning: stage[...] = (src<<9)|(dst&511), grouped by coarse bucket.
// All global stores are contiguous runs of FLUSH_G..BIN_CAP ints by one thread.
__global__ __launch_bounds__(256) void stage_bin(const int* __restrict__ ei,
                                                 int* __restrict__ gcur,
                                                 int* __restrict__ stage,
                                                 int E, int B, int per_block) {
    __shared__ int bin_cnt[MAXB];
    __shared__ int bin_buf[MAXB * BIN_CAP];   // ~50KB
    for (int i = threadIdx.x; i < B; i += blockDim.x) bin_cnt[i] = 0;
    __syncthreads();
    int base = blockIdx.x * per_block;
    int end  = min(E, base + per_block);
    for (int it = base; it < end; it += blockDim.x) {
        int e = it + (int)threadIdx.x;
        if (e < end) {
            int s = ei[e];
            int d = ei[E + e];
            int b = d >> SBSH;
            int val = (s << SBSH) | (d & (SBW - 1));
            int pos = atomicAdd(&bin_cnt[b], 1);
            if (pos < BIN_CAP) {
                bin_buf[b * BIN_CAP + pos] = val;
            } else {                                  // overflow (P ~ 1e-15): direct store
                int gp = atomicAdd(&gcur[b], 1);
                stage[gp] = val;
            }
        }
        __syncthreads();
        for (int b2 = threadIdx.x; b2 < B; b2 += blockDim.x) {
            int c = min(bin_cnt[b2], BIN_CAP);
            if (c >= FLUSH_G) {
                int m = c & ~(FLUSH_G - 1);
                int r = atomicAdd(&gcur[b2], m);
                const int* src = &bin_buf[b2 * BIN_CAP];
                for (int k = 0; k < m; k++) stage[r + k] = src[k];       // contiguous run
                for (int k = m; k < c; k++) bin_buf[b2 * BIN_CAP + (k - m)] = src[k];
                bin_cnt[b2] = c - m;
            } else {
                bin_cnt[b2] = c;
            }
        }
        __syncthreads();
    }
    for (int b2 = threadIdx.x; b2 < B; b2 += blockDim.x) {   // final flush
        int c = min(bin_cnt[b2], BIN_CAP);
        if (c > 0) {
            int r = atomicAdd(&gcur[b2], c);
            for (int k = 0; k < c; k++) stage[r + k] = bin_buf[b2 * BIN_CAP + k];
        }
    }
}

// one block per coarse bucket: LDS prefix-scan of cnt -> row_start + dis, then
// scatter src into the bucket's ~64KB CSR segment (single-CU-owned, L2-merged)
__global__ __launch_bounds__(256) void scatter_csr(const int* __restrict__ stage,
                                                   const int* __restrict__ coarse_start,
                                                   const int* __restrict__ coarse_cnt,
                                                   const int* __restrict__ cnt,
                                                   float* __restrict__ dis,
                                                   int* __restrict__ row_start,
                                                   int* __restrict__ csr, int n) {
    __shared__ int s0[SBW], s1[SBW];
    int b  = blockIdx.x;
    int nb = b << SBSH;
    int i0 = threadIdx.x, i1 = threadIdx.x + 256;
    int c0 = (nb + i0 < n) ? cnt[nb + i0] : 0;
    int c1 = (nb + i1 < n) ? cnt[nb + i1] : 0;
    s0[i0] = c0; s0[i1] = c1;
    if (nb + i0 < n) dis[nb + i0] = rsqrtf((float)(c0 + 1));
    if (nb + i1 < n) dis[nb + i1] = rsqrtf((float)(c1 + 1));
    __syncthreads();
    int* src = s0; int* dst = s1;
    for (int off = 1; off < SBW; off <<= 1) {       // Hillis-Steele inclusive scan
        int v0 = src[i0] + ((i0 >= off) ? src[i0 - off] : 0);
        int v1 = src[i1] + ((i1 >= off) ? src[i1 - off] : 0);
        dst[i0] = v0; dst[i1] = v1;
        __syncthreads();
        int* t = src; src = dst; dst = t;
    }
    int base = coarse_start[b];
    int e0 = base + src[i0] - c0;                    // exclusive scan
    int e1 = base + src[i1] - c1;
    if (nb + i0 < n) row_start[nb + i0] = e0;
    if (nb + i1 < n) row_start[nb + i1] = e1;
    dst[i0] = e0; dst[i1] = e1;                      // dst becomes the cursor array
    __syncthreads();
    int num = coarse_cnt[b];
    for (int k = threadIdx.x; k < num; k += blockDim.x) {
        int v = stage[base + k];
        int pos = atomicAdd(&dst[v & (SBW - 1)], 1);
        csr[pos] = v >> SBSH;
    }
}

// ---------------- layer-1 GEMM: g1 = (x @ W1) * dis ----------------
__global__ __launch_bounds__(256) void gemm1(const float* __restrict__ x,
                                             const float* __restrict__ W1,
                                             const float* __restrict__ dis,
                                             float* __restrict__ g1, int n) {
    __shared__ float w[F_IN * F_HID];  // 4 KB
    for (int i = threadIdx.x; i < F_IN * F_HID; i += blockDim.x) w[i] = W1[i];
    __syncthreads();
    int node = blockIdx.x * blockDim.x + threadIdx.x;
    if (node >= n) return;
    const float4* xr = (const float4*)(x + (size_t)node * F_IN);
    float acc[F_HID];
#pragma unroll
    for (int f = 0; f < F_HID; f++) acc[f] = 0.0f;
#pragma unroll
    for (int j = 0; j < F_IN / 4; j++) {
        float4 v = xr[j];
        const float* wr = &w[j * 4 * F_HID];
#pragma unroll
        for (int f = 0; f < F_HID; f++)
            acc[f] += v.x * wr[f] + v.y * wr[F_HID + f] + v.z * wr[2 * F_HID + f] + v.w * wr[3 * F_HID + f];
    }
    float d = dis[node];
    float4* gp = (float4*)(g1 + (size_t)node * F_HID);
    gp[0] = make_float4(acc[0] * d, acc[1] * d, acc[2] * d, acc[3] * d);
    gp[1] = make_float4(acc[4] * d, acc[5] * d, acc[6] * d, acc[7] * d);
}

// ---------------- aggregation: agg[i] = dis[i] * (sum g[src] + g[i]); 8 lanes/node ----------------
__global__ __launch_bounds__(256) void aggregate(const int* __restrict__ csr,
                                                 const int* __restrict__ row_start,
                                                 const int* __restrict__ cnt,
                                                 const float* __restrict__ dis,
                                                 const float* __restrict__ g,
                                                 float* __restrict__ agg, int n) {
    int t = blockIdx.x * blockDim.x + threadIdx.x;
    int node = t >> 3;
    int f = t & 7;
    if (node >= n) return;
    int beg = row_start[node];
    int c   = cnt[node];
    float acc = g[(size_t)node * F_HID + f];        // self-loop
    for (int j = 0; j < c; j++) {
        int s = csr[beg + j];                       // uniform across the 8-lane group
        acc += g[(size_t)s * F_HID + f];
    }
    agg[(size_t)node * F_HID + f] = acc * dis[node];
}

// ---------------- g2 = relu(agg1 + b1) * dis ----------------
__global__ __launch_bounds__(256) void relu_init(const float* __restrict__ b1,
                                                 const float* __restrict__ dis,
                                                 const float* __restrict__ agg1,
                                                 float* __restrict__ g2, int n) {
    int i = blockIdx.x * blockDim.x + threadIdx.x;
    if (i >= n) return;
    float d = dis[i];
    const float4* a = (const float4*)(agg1 + (size_t)i * F_HID);
    float4 lo = a[0], hi = a[1];
    lo.x = fmaxf(lo.x + b1[0], 0.0f) * d;
    lo.y = fmaxf(lo.y + b1[1], 0.0f) * d;
    lo.z = fmaxf(lo.z + b1[2], 0.0f) * d;
    lo.w = fmaxf(lo.w + b1[3], 0.0f) * d;
    hi.x = fmaxf(hi.x + b1[4], 0.0f) * d;
    hi.y = fmaxf(hi.y + b1[5], 0.0f) * d;
    hi.z = fmaxf(hi.z + b1[6], 0.0f) * d;
    hi.w = fmaxf(hi.w + b1[7], 0.0f) * d;
    float4* o = (float4*)(g2 + (size_t)i * F_HID);
    o[0] = lo; o[1] = hi;
}

// ---------------- out = agg2 @ W2 + b2 ----------------
__global__ __launch_bounds__(256) void gemm2(const float* __restrict__ agg2,
                                             const float* __restrict__ W2,
                                             const float* __restrict__ b2,
                                             float* __restrict__ out, int n) {
    __shared__ float w[F_HID * F_OUT];
    __shared__ float bb[F_OUT];
    if (threadIdx.x < F_HID * F_OUT) w[threadIdx.x] = W2[threadIdx.x];
    if (threadIdx.x < F_OUT) bb[threadIdx.x] = b2[threadIdx.x];
    __syncthreads();
    int node = blockIdx.x * blockDim.x + threadIdx.x;
    if (node >= n) return;
    const float4* ap = (const float4*)(agg2 + (size_t)node * F_HID);
    float4 lo = ap[0], hi = ap[1];
    float a[F_HID] = {lo.x, lo.y, lo.z, lo.w, hi.x, hi.y, hi.z, hi.w};
    float o[F_OUT];
#pragma unroll
    for (int f = 0; f < F_OUT; f++) o[f] = bb[f];
#pragma unroll
    for (int k = 0; k < F_HID; k++) {
#pragma unroll
        for (int f = 0; f < F_OUT; f++) o[f] += a[k] * w[k * F_OUT + f];
    }
    float4* op = (float4*)(out + (size_t)node * F_OUT);
    op[0] = make_float4(o[0], o[1], o[2], o[3]);
    op[1] = make_float4(o[4], o[5], o[6], o[7]);
    op[2] = make_float4(o[8], o[9], o[10], o[11]);
    op[3] = make_float4(o[12], o[13], o[14], o[15]);
}

extern "C" void kernel_launch(void* const* d_in, const int* in_sizes, int n_in,
                              void* d_out, int out_size, void* d_ws, size_t ws_size,
                              hipStream_t stream) {
    const float* x  = (const float*)d_in[0];
    const int*   ei = (const int*)d_in[1];
    const float* W1 = (const float*)d_in[2];
    const float* b1 = (const float*)d_in[3];
    const float* W2 = (const float*)d_in[4];
    const float* b2 = (const float*)d_in[5];
    float* out = (float*)d_out;

    const int N = in_sizes[0] / F_IN;
    const int E = in_sizes[1] / 2;
    const int B = (N + SBW - 1) >> SBSH;   // 391 for N=200000

    // ws (4B units): stage[E] | csr[E] | dis[N] | bufA[8N] | bufB[8N] | cnt[N] | row_start[N]
    //                | coarse_start[B] | coarse_cnt[B] | gcur[B] | cursor[1]
    int*   stage        = (int*)d_ws;
    int*   csr          = stage + E;
    float* dis          = (float*)(csr + E);
    float* bufA         = dis + N;
    float* bufB         = bufA + (size_t)N * F_HID;
    int*   cnt          = (int*)(bufB + (size_t)N * F_HID);
    int*   row_start    = cnt + N;
    int*   coarse_start = row_start + N;
    int*   coarse_cnt   = coarse_start + B;
    int*   gcur         = coarse_cnt + B;
    int*   cursor       = gcur + B;

    const int BT = 256;
    dim3 blkN((N + BT - 1) / BT), thr(BT);
    dim3 blkE4((E / 4 + BT) / BT);
    dim3 blkA(((size_t)N * F_HID + BT - 1) / BT);

    const int SBLK = 768;                          // ~3 blocks/CU at 51KB LDS
    const int per_block = (E + SBLK - 1) / SBLK;

    init_cnt    <<<blkN,  thr, 0, stream>>>(cnt, cursor, N);
    count_dst   <<<blkE4, thr, 0, stream>>>(ei, cnt, E);
    bucket_alloc<<<dim3(B), thr, 0, stream>>>(cnt, coarse_start, coarse_cnt, gcur, cursor, N);
    stage_bin   <<<dim3(SBLK), thr, 0, stream>>>(ei, gcur, stage, E, B, per_block);
    scatter_csr <<<dim3(B), thr, 0, stream>>>(stage, coarse_start, coarse_cnt, cnt, dis, row_start, csr, N);
    gemm1       <<<blkN,  thr, 0, stream>>>(x, W1, dis, bufA, N);
    aggregate   <<<blkA,  thr, 0, stream>>>(csr, row_start, cnt, dis, bufA, bufB, N);
    relu_init   <<<blkN,  thr, 0, stream>>>(b1, dis, bufB, bufA, N);
    aggregate   <<<blkA,  thr, 0, stream>>>(csr, row_start, cnt, dis, bufA, bufB, N);
    gemm2       <<<blkN,  thr, 0, stream>>>(bufB, W2, b2, out, N);
}

// Round 8
// 714.402 us; speedup vs baseline: 1.8079x; 1.2904x over previous
//
#include <hip/hip_runtime.h>

#define F_IN  128
#define F_HID 8
#define F_OUT 16

#define SBSH  9                 // coarse bucket = 512 consecutive dst nodes
#define SBW   (1 << SBSH)
#define MAXB  400               // supports N <= 204800
#define BIN_CAP  32             // LDS entries per bucket (stage_bin)
#define FLUSH_G  16             // flush granularity (16 ints = 64B line)

// edge_index arrives as int32 [2][E].
// agg[i] = dis[i] * ( sum_{s in N(i)} g[s] + g[i] ),  g = h * dis.
// Session law (R3-R7): any scattered 4B global store/atomic costs ~64B of
// cross-XCD partial-line writeback. Therefore: NO per-node global atomics
// anywhere. Counting is per-block LDS hist (coarse) + per-bucket LDS hist
// (fine, inside scatter_csr); all CSR-build stores are LDS-write-combined runs.

// per-block LDS histogram over coarse buckets; one coalesced flush per block
__global__ __launch_bounds__(256) void coarse_count(const int* __restrict__ ei,
                                                    int* __restrict__ coarse_cnt,
                                                    int E, int B) {
    __shared__ int hist[MAXB];
    for (int i = threadIdx.x; i < B; i += blockDim.x) hist[i] = 0;
    __syncthreads();
    const int4* d4 = (const int4*)(ei + E);
    int n4 = E >> 2;
    int stride = gridDim.x * blockDim.x;
    for (int idx = blockIdx.x * blockDim.x + threadIdx.x; idx < n4; idx += stride) {
        int4 v = d4[idx];
        atomicAdd(&hist[v.x >> SBSH], 1);
        atomicAdd(&hist[v.y >> SBSH], 1);
        atomicAdd(&hist[v.z >> SBSH], 1);
        atomicAdd(&hist[v.w >> SBSH], 1);
    }
    if (blockIdx.x == 0) {   // tail (E not multiple of 4)
        for (int k = (n4 << 2) + threadIdx.x; k < E; k += blockDim.x)
            atomicAdd(&hist[ei[E + k] >> SBSH], 1);
    }
    __syncthreads();
    for (int i = threadIdx.x; i < B; i += blockDim.x)
        if (hist[i]) atomicAdd(&coarse_cnt[i], hist[i]);
}

__global__ void init_coarse(int* __restrict__ coarse_cnt, int B) {
    int i = blockIdx.x * blockDim.x + threadIdx.x;
    if (i < B) coarse_cnt[i] = 0;
}

// single block: exclusive scan of coarse_cnt -> coarse_start, gcur (deterministic)
__global__ __launch_bounds__(256) void bucket_scan(const int* __restrict__ coarse_cnt,
                                                   int* __restrict__ coarse_start,
                                                   int* __restrict__ gcur, int B) {
    __shared__ int s0[SBW], s1[SBW];
    int i0 = threadIdx.x, i1 = threadIdx.x + 256;
    int c0 = (i0 < B) ? coarse_cnt[i0] : 0;
    int c1 = (i1 < B) ? coarse_cnt[i1] : 0;
    s0[i0] = c0; s0[i1] = c1;
    __syncthreads();
    int* src = s0; int* dst = s1;
    for (int off = 1; off < SBW; off <<= 1) {
        int v0 = src[i0] + ((i0 >= off) ? src[i0 - off] : 0);
        int v1 = src[i1] + ((i1 >= off) ? src[i1 - off] : 0);
        dst[i0] = v0; dst[i1] = v1;
        __syncthreads();
        int* t = src; src = dst; dst = t;
    }
    if (i0 < B) { int e = src[i0] - c0; coarse_start[i0] = e; gcur[i0] = e; }
    if (i1 < B) { int e = src[i1] - c1; coarse_start[i1] = e; gcur[i1] = e; }
}

// LDS write-combined binning: stage[...] = (src<<9)|(dst&511), grouped by coarse bucket.
__global__ __launch_bounds__(256) void stage_bin(const int* __restrict__ ei,
                                                 int* __restrict__ gcur,
                                                 int* __restrict__ stage,
                                                 int E, int B, int per_block) {
    __shared__ int bin_cnt[MAXB];
    __shared__ int bin_buf[MAXB * BIN_CAP];   // ~50KB
    for (int i = threadIdx.x; i < B; i += blockDim.x) bin_cnt[i] = 0;
    __syncthreads();
    int base = blockIdx.x * per_block;
    int end  = min(E, base + per_block);
    for (int it = base; it < end; it += blockDim.x) {
        int e = it + (int)threadIdx.x;
        if (e < end) {
            int s = ei[e];
            int d = ei[E + e];
            int b = d >> SBSH;
            int val = (s << SBSH) | (d & (SBW - 1));
            int pos = atomicAdd(&bin_cnt[b], 1);
            if (pos < BIN_CAP) {
                bin_buf[b * BIN_CAP + pos] = val;
            } else {                                  // overflow (P ~ 1e-15): direct store
                int gp = atomicAdd(&gcur[b], 1);
                stage[gp] = val;
            }
        }
        __syncthreads();
        for (int b2 = threadIdx.x; b2 < B; b2 += blockDim.x) {
            int c = min(bin_cnt[b2], BIN_CAP);
            if (c >= FLUSH_G) {
                int m = c & ~(FLUSH_G - 1);
                int r = atomicAdd(&gcur[b2], m);
                const int* src = &bin_buf[b2 * BIN_CAP];
                for (int k = 0; k < m; k++) stage[r + k] = src[k];       // contiguous run
                for (int k = m; k < c; k++) bin_buf[b2 * BIN_CAP + (k - m)] = src[k];
                bin_cnt[b2] = c - m;
            } else {
                bin_cnt[b2] = c;
            }
        }
        __syncthreads();
    }
    for (int b2 = threadIdx.x; b2 < B; b2 += blockDim.x) {   // final flush
        int c = min(bin_cnt[b2], BIN_CAP);
        if (c > 0) {
            int r = atomicAdd(&gcur[b2], c);
            for (int k = 0; k < c; k++) stage[r + k] = bin_buf[b2 * BIN_CAP + k];
        }
    }
}

// one block per coarse bucket: LDS per-node hist from stage -> cnt/dis, scan ->
// row_start, then scatter src into the bucket's warm CSR segment
__global__ __launch_bounds__(256) void scatter_csr(const int* __restrict__ stage,
                                                   const int* __restrict__ coarse_start,
                                                   const int* __restrict__ coarse_cnt,
                                                   int* __restrict__ cnt,
                                                   float* __restrict__ dis,
                                                   int* __restrict__ row_start,
                                                   int* __restrict__ csr, int n) {
    __shared__ int s0[SBW], s1[SBW];
    int b  = blockIdx.x;
    int nb = b << SBSH;
    int i0 = threadIdx.x, i1 = threadIdx.x + 256;
    s0[i0] = 0; s0[i1] = 0;
    __syncthreads();
    int base = coarse_start[b];
    int num  = coarse_cnt[b];
    for (int k = threadIdx.x; k < num; k += blockDim.x)
        atomicAdd(&s0[stage[base + k] & (SBW - 1)], 1);
    __syncthreads();
    int c0 = s0[i0], c1 = s0[i1];
    if (nb + i0 < n) { cnt[nb + i0] = c0; dis[nb + i0] = rsqrtf((float)(c0 + 1)); }
    if (nb + i1 < n) { cnt[nb + i1] = c1; dis[nb + i1] = rsqrtf((float)(c1 + 1)); }
    int* src = s0; int* dst = s1;
    for (int off = 1; off < SBW; off <<= 1) {       // Hillis-Steele inclusive scan
        int v0 = src[i0] + ((i0 >= off) ? src[i0 - off] : 0);
        int v1 = src[i1] + ((i1 >= off) ? src[i1 - off] : 0);
        dst[i0] = v0; dst[i1] = v1;
        __syncthreads();
        int* t = src; src = dst; dst = t;
    }
    int e0 = base + src[i0] - c0;                    // exclusive scan
    int e1 = base + src[i1] - c1;
    if (nb + i0 < n) row_start[nb + i0] = e0;
    if (nb + i1 < n) row_start[nb + i1] = e1;
    dst[i0] = e0; dst[i1] = e1;                      // dst becomes the cursor array
    __syncthreads();
    for (int k = threadIdx.x; k < num; k += blockDim.x) {
        int v = stage[base + k];
        int pos = atomicAdd(&dst[v & (SBW - 1)], 1);
        csr[pos] = v >> SBSH;
    }
}

// ---------------- layer-1 GEMM: g1 = (x @ W1) * dis ----------------
__global__ __launch_bounds__(256) void gemm1(const float* __restrict__ x,
                                             const float* __restrict__ W1,
                                             const float* __restrict__ dis,
                                             float* __restrict__ g1, int n) {
    __shared__ float w[F_IN * F_HID];  // 4 KB
    for (int i = threadIdx.x; i < F_IN * F_HID; i += blockDim.x) w[i] = W1[i];
    __syncthreads();
    int node = blockIdx.x * blockDim.x + threadIdx.x;
    if (node >= n) return;
    const float4* xr = (const float4*)(x + (size_t)node * F_IN);
    float acc[F_HID];
#pragma unroll
    for (int f = 0; f < F_HID; f++) acc[f] = 0.0f;
#pragma unroll
    for (int j = 0; j < F_IN / 4; j++) {
        float4 v = xr[j];
        const float* wr = &w[j * 4 * F_HID];
#pragma unroll
        for (int f = 0; f < F_HID; f++)
            acc[f] += v.x * wr[f] + v.y * wr[F_HID + f] + v.z * wr[2 * F_HID + f] + v.w * wr[3 * F_HID + f];
    }
    float d = dis[node];
    float4* gp = (float4*)(g1 + (size_t)node * F_HID);
    gp[0] = make_float4(acc[0] * d, acc[1] * d, acc[2] * d, acc[3] * d);
    gp[1] = make_float4(acc[4] * d, acc[5] * d, acc[6] * d, acc[7] * d);
}

// ---------------- aggregation: agg[i] = dis[i] * (sum g[src] + g[i]); 8 lanes/node ----------------
__global__ __launch_bounds__(256) void aggregate(const int* __restrict__ csr,
                                                 const int* __restrict__ row_start,
                                                 const int* __restrict__ cnt,
                                                 const float* __restrict__ dis,
                                                 const float* __restrict__ g,
                                                 float* __restrict__ agg, int n) {
    int t = blockIdx.x * blockDim.x + threadIdx.x;
    int node = t >> 3;
    int f = t & 7;
    if (node >= n) return;
    int beg = row_start[node];
    int c   = cnt[node];
    float acc = g[(size_t)node * F_HID + f];        // self-loop
    for (int j = 0; j < c; j++) {
        int s = csr[beg + j];                       // uniform across the 8-lane group
        acc += g[(size_t)s * F_HID + f];
    }
    agg[(size_t)node * F_HID + f] = acc * dis[node];
}

// ---------------- g2 = relu(agg1 + b1) * dis ----------------
__global__ __launch_bounds__(256) void relu_init(const float* __restrict__ b1,
                                                 const float* __restrict__ dis,
                                                 const float* __restrict__ agg1,
                                                 float* __restrict__ g2, int n) {
    int i = blockIdx.x * blockDim.x + threadIdx.x;
    if (i >= n) return;
    float d = dis[i];
    const float4* a = (const float4*)(agg1 + (size_t)i * F_HID);
    float4 lo = a[0], hi = a[1];
    lo.x = fmaxf(lo.x + b1[0], 0.0f) * d;
    lo.y = fmaxf(lo.y + b1[1], 0.0f) * d;
    lo.z = fmaxf(lo.z + b1[2], 0.0f) * d;
    lo.w = fmaxf(lo.w + b1[3], 0.0f) * d;
    hi.x = fmaxf(hi.x + b1[4], 0.0f) * d;
    hi.y = fmaxf(hi.y + b1[5], 0.0f) * d;
    hi.z = fmaxf(hi.z + b1[6], 0.0f) * d;
    hi.w = fmaxf(hi.w + b1[7], 0.0f) * d;
    float4* o = (float4*)(g2 + (size_t)i * F_HID);
    o[0] = lo; o[1] = hi;
}

// ---------------- out = agg2 @ W2 + b2 ----------------
__global__ __launch_bounds__(256) void gemm2(const float* __restrict__ agg2,
                                             const float* __restrict__ W2,
                                             const float* __restrict__ b2,
                                             float* __restrict__ out, int n) {
    __shared__ float w[F_HID * F_OUT];
    __shared__ float bb[F_OUT];
    if (threadIdx.x < F_HID * F_OUT) w[threadIdx.x] = W2[threadIdx.x];
    if (threadIdx.x < F_OUT) bb[threadIdx.x] = b2[threadIdx.x];
    __syncthreads();
    int node = blockIdx.x * blockDim.x + threadIdx.x;
    if (node >= n) return;
    const float4* ap = (const float4*)(agg2 + (size_t)node * F_HID);
    float4 lo = ap[0], hi = ap[1];
    float a[F_HID] = {lo.x, lo.y, lo.z, lo.w, hi.x, hi.y, hi.z, hi.w};
    float o[F_OUT];
#pragma unroll
    for (int f = 0; f < F_OUT; f++) o[f] = bb[f];
#pragma unroll
    for (int k = 0; k < F_HID; k++) {
#pragma unroll
        for (int f = 0; f < F_OUT; f++) o[f] += a[k] * w[k * F_OUT + f];
    }
    float4* op = (float4*)(out + (size_t)node * F_OUT);
    op[0] = make_float4(o[0], o[1], o[2], o[3]);
    op[1] = make_float4(o[4], o[5], o[6], o[7]);
    op[2] = make_float4(o[8], o[9], o[10], o[11]);
    op[3] = make_float4(o[12], o[13], o[14], o[15]);
}

extern "C" void kernel_launch(void* const* d_in, const int* in_sizes, int n_in,
                              void* d_out, int out_size, void* d_ws, size_t ws_size,
                              hipStream_t stream) {
    const float* x  = (const float*)d_in[0];
    const int*   ei = (const int*)d_in[1];
    const float* W1 = (const float*)d_in[2];
    const float* b1 = (const float*)d_in[3];
    const float* W2 = (const float*)d_in[4];
    const float* b2 = (const float*)d_in[5];
    float* out = (float*)d_out;

    const int N = in_sizes[0] / F_IN;
    const int E = in_sizes[1] / 2;
    const int B = (N + SBW - 1) >> SBSH;   // 391 for N=200000

    // ws (4B units): stage[E] | csr[E] | dis[N] | bufA[8N] | bufB[8N] | cnt[N] | row_start[N]
    //                | coarse_start[B] | coarse_cnt[B] | gcur[B]
    int*   stage        = (int*)d_ws;
    int*   csr          = stage + E;
    float* dis          = (float*)(csr + E);
    float* bufA         = dis + N;
    float* bufB         = bufA + (size_t)N * F_HID;
    int*   cnt          = (int*)(bufB + (size_t)N * F_HID);
    int*   row_start    = cnt + N;
    int*   coarse_start = row_start + N;
    int*   coarse_cnt   = coarse_start + B;
    int*   gcur         = coarse_cnt + B;

    const int BT = 256;
    dim3 blkN((N + BT - 1) / BT), thr(BT);
    dim3 blkA(((size_t)N * F_HID + BT - 1) / BT);

    const int SBLK = 768;                          // ~3 blocks/CU at 51KB LDS
    const int per_block = (E + SBLK - 1) / SBLK;

    init_coarse <<<dim3((B + BT - 1) / BT), thr, 0, stream>>>(coarse_cnt, B);
    coarse_count<<<dim3(256), thr, 0, stream>>>(ei, coarse_cnt, E, B);
    bucket_scan <<<dim3(1),   thr, 0, stream>>>(coarse_cnt, coarse_start, gcur, B);
    stage_bin   <<<dim3(SBLK), thr, 0, stream>>>(ei, gcur, stage, E, B, per_block);
    scatter_csr <<<dim3(B),   thr, 0, stream>>>(stage, coarse_start, coarse_cnt, cnt, dis, row_start, csr, N);
    gemm1       <<<blkN,  thr, 0, stream>>>(x, W1, dis, bufA, N);
    aggregate   <<<blkA,  thr, 0, stream>>>(csr, row_start, cnt, dis, bufA, bufB, N);
    relu_init   <<<blkN,  thr, 0, stream>>>(b1, dis, bufB, bufA, N);
    aggregate   <<<blkA,  thr, 0, stream>>>(csr, row_start, cnt, dis, bufA, bufB, N);
    gemm2       <<<blkN,  thr, 0, stream>>>(bufB, W2, b2, out, N);
}